// Round 4
// baseline (82.520 us; speedup 1.0000x reference)
//
#include <hip/hip_runtime.h>
#include <hip/hip_bf16.h>

// MiniBatchDiscrimination via bf16 MFMA (gfx950).
// x: [32,16,16,256] f32, T: [256,64,8] f32, out: [32,16,16,320] f32.
// Kernel 1 (pack_T): T [256k][512t] f32 -> B-fragments, frag-packed bf16:
//   Tf[(tt*8+kt)*64 + lane] = 8 bf16 {B[kt*32+(l>>4)*8+j][tt*16+(l&15)]}.
// Kernel 2 (mbd_main): 256 blocks (one per pixel) x 512 threads:
//   stage x -> LDS A-frags (bf16) + f32 passthrough, 64 MFMAs/wave,
//   M tile bf16 in LDS, pairwise exp(-L1), coalesced o_b epilogue.

namespace {
constexpr int kN = 32;
constexpr int kHW = 256;
constexpr int kF = 256;          // GEMM K
constexpr int kOutRow = 320;
constexpr int kMstride = 520;    // 512 + 8 pad (ushorts), 16B-aligned rows
}

using frag_ab = __attribute__((ext_vector_type(8))) short;   // 8 bf16
using frag_cd = __attribute__((ext_vector_type(4))) float;   // 4 f32

__device__ inline unsigned short f2bf(float f) {
  union { __hip_bfloat16 h; unsigned short u; } c;
  c.h = __float2bfloat16(f);
  return c.u;
}

__device__ inline void unpack8(const uint4& m, float* f) {
  f[0] = __uint_as_float(m.x << 16);  f[1] = __uint_as_float(m.x & 0xffff0000u);
  f[2] = __uint_as_float(m.y << 16);  f[3] = __uint_as_float(m.y & 0xffff0000u);
  f[4] = __uint_as_float(m.z << 16);  f[5] = __uint_as_float(m.z & 0xffff0000u);
  f[6] = __uint_as_float(m.w << 16);  f[7] = __uint_as_float(m.w & 0xffff0000u);
}

// ---- Kernel 1: pack T into MFMA B-fragments (no LDS, no barriers) ----
__global__ __launch_bounds__(256)
void pack_T(const float* __restrict__ T, uint4* __restrict__ Tf) {
  const int g = blockIdx.x * 256 + threadIdx.x;  // 0..16383
  const int l = g & 63;
  const int frag = g >> 6;                       // 0..255 = tt*8 + kt
  const int tt = frag >> 3, kt = frag & 7;
  const int col = tt * 16 + (l & 15);
  const int k0 = kt * 32 + (l >> 4) * 8;
  unsigned p[4];
#pragma unroll
  for (int jj = 0; jj < 4; ++jj) {
    float a = T[(size_t)(k0 + jj * 2) * 512 + col];
    float b = T[(size_t)(k0 + jj * 2 + 1) * 512 + col];
    p[jj] = (unsigned)f2bf(a) | ((unsigned)f2bf(b) << 16);
  }
  Tf[g] = make_uint4(p[0], p[1], p[2], p[3]);
}

// ---- Kernel 2: fused GEMM + pairwise ----
__global__ __launch_bounds__(512, 2)
void mbd_main(const float* __restrict__ x, const uint4* __restrict__ Tf,
              float* __restrict__ out) {
  __shared__ uint4 Afrag[2 * 8 * 64];                      // 16 KB, dead after MFMA
  __shared__ __align__(16) unsigned short Mlds[kN * kMstride];  // 33.3 KB
  float* obuf = (float*)Afrag;                             // [32][68] aliased
  const int hw = blockIdx.x;
  const int tid = threadIdx.x;
  const int l = tid & 63, w = tid >> 6;

  // Phase 1: stage x -> A-frags (bf16) + full f32 passthrough.
  const float4* x4 = (const float4*)x;
  float4* out4 = (float4*)out;
#pragma unroll
  for (int s = 0; s < 2; ++s) {
    const int task = tid + s * 512;        // 1024 tasks: 32 n x 32 k-groups
    const int n = task >> 5;
    const int k8 = task & 31;              // group of 8 k
    const size_t xb = (size_t)n * (kHW * kF / 4) + (size_t)hw * (kF / 4) + k8 * 2;
    float4 v0 = x4[xb];
    float4 v1 = x4[xb + 1];
    const size_t ob = (size_t)(n * kHW + hw) * (kOutRow / 4) + k8 * 2;
    out4[ob] = v0;
    out4[ob + 1] = v1;
    uint4 p;
    p.x = (unsigned)f2bf(v0.x) | ((unsigned)f2bf(v0.y) << 16);
    p.y = (unsigned)f2bf(v0.z) | ((unsigned)f2bf(v0.w) << 16);
    p.z = (unsigned)f2bf(v1.x) | ((unsigned)f2bf(v1.y) << 16);
    p.w = (unsigned)f2bf(v1.z) | ((unsigned)f2bf(v1.w) << 16);
    const int rt = n >> 4, kt = k8 >> 2, ln = (n & 15) | ((k8 & 3) << 4);
    Afrag[(rt * 8 + kt) * 64 + ln] = p;
  }
  __syncthreads();

  // Phase 2: MFMA GEMM. Wave w owns t-tiles 4w..4w+3 (64 cols of 512).
  frag_cd acc[4][2] = {};                  // [q][rt]
#pragma unroll
  for (int kt = 0; kt < 8; ++kt) {
    uint4 a0 = Afrag[(0 * 8 + kt) * 64 + l];
    uint4 a1 = Afrag[(1 * 8 + kt) * 64 + l];
    frag_ab af0 = __builtin_bit_cast(frag_ab, a0);
    frag_ab af1 = __builtin_bit_cast(frag_ab, a1);
#pragma unroll
    for (int q = 0; q < 4; ++q) {
      const int tT = w * 4 + q;
      uint4 b = Tf[(tT * 8 + kt) * 64 + l];    // contiguous 1 KB per wave
      frag_ab bf = __builtin_bit_cast(frag_ab, b);
      acc[q][0] = __builtin_amdgcn_mfma_f32_16x16x32_bf16(af0, bf, acc[q][0], 0, 0, 0);
      acc[q][1] = __builtin_amdgcn_mfma_f32_16x16x32_bf16(af1, bf, acc[q][1], 0, 0, 0);
    }
  }
  __syncthreads();   // Afrag reads done (safe to reuse as obuf later)

  // Phase 3a: park M (bf16). C/D layout: col = l&15, row = (l>>4)*4 + reg.
#pragma unroll
  for (int q = 0; q < 4; ++q)
#pragma unroll
    for (int rt = 0; rt < 2; ++rt)
#pragma unroll
      for (int r = 0; r < 4; ++r) {
        const int n = rt * 16 + (l >> 4) * 4 + r;
        const int t = (w * 4 + q) * 16 + (l & 15);
        Mlds[n * kMstride + t] = f2bf(acc[q][rt][r]);
      }
  __syncthreads();

  // Phase 3b: pairwise exp(-L1). Thread: b in {bA, bA+32}, i in {i0, i0+1}.
  const int bA = tid >> 4;                 // 0..31
  const int i0 = (tid & 15) * 2;
  float mi[2][2][8];                       // [bsel][ii][c]
#pragma unroll
  for (int bs = 0; bs < 2; ++bs)
#pragma unroll
    for (int ii = 0; ii < 2; ++ii) {
      uint4 m = *(const uint4*)&Mlds[(i0 + ii) * kMstride + (bA + bs * 32) * 8];
      unpack8(m, mi[bs][ii]);
    }
  float ob[2][2] = {};
#pragma unroll 4
  for (int j = 0; j < kN; ++j) {
#pragma unroll
    for (int bs = 0; bs < 2; ++bs) {
      uint4 m = *(const uint4*)&Mlds[j * kMstride + (bA + bs * 32) * 8];
      float mj[8];
      unpack8(m, mj);
#pragma unroll
      for (int ii = 0; ii < 2; ++ii) {
        float nrm = 0.f;
#pragma unroll
        for (int c = 0; c < 8; ++c) nrm += fabsf(mi[bs][ii][c] - mj[c]);
        ob[bs][ii] += __expf(-nrm);
      }
    }
  }
  // Stage o_b in LDS (aliased over dead Afrag), then coalesced float4 stores.
#pragma unroll
  for (int bs = 0; bs < 2; ++bs)
#pragma unroll
    for (int ii = 0; ii < 2; ++ii)
      obuf[(i0 + ii) * 68 + bA + bs * 32] = ob[bs][ii];
  __syncthreads();
  {
    const int n = tid >> 4;                // 0..31
    const int b4 = tid & 15;               // float4 index into 64 b's
    float4 v = *(const float4*)&obuf[n * 68 + b4 * 4];
    out4[(size_t)(n * kHW + hw) * (kOutRow / 4) + (kF / 4) + b4] = v;
  }
}

extern "C" void kernel_launch(void* const* d_in, const int* in_sizes, int n_in,
                              void* d_out, int out_size, void* d_ws, size_t ws_size,
                              hipStream_t stream) {
  const float* x = (const float*)d_in[0];     // [32,16,16,256]
  const float* T = (const float*)d_in[1];     // [256,64,8] = [256][512]
  float* out = (float*)d_out;                 // [32,16,16,320]
  uint4* Tf = (uint4*)d_ws;                   // 256 KB of B-fragments
  (void)in_sizes; (void)n_in; (void)out_size; (void)ws_size;
  pack_T<<<dim3(64), dim3(256), 0, stream>>>(T, Tf);
  mbd_main<<<dim3(kHW), dim3(512), 0, stream>>>(x, Tf, out);
}

// Round 5
// 77.199 us; speedup vs baseline: 1.0689x; 1.0689x over previous
//
#include <hip/hip_runtime.h>
#include <hip/hip_bf16.h>

// MiniBatchDiscrimination via bf16 MFMA (gfx950).
// x: [32,16,16,256] f32, T: [256,64,8] f32, out: [32,16,16,320] f32.
// Kernel 1 (pack_T): T [256k][512t] f32 -> B-fragments bf16 in d_ws:
//   Tf[(tt*8+kt)*64 + l] = {B[kt*32+(l>>4)*8+j][tt*16+(l&15)], j=0..7}.
// Kernel 2 (mbd_main): grid 1024 = (pixel, t-quarter), 256 threads, 4 blocks/CU:
//   prefetch Tf frags to regs -> stage x to LDS A-frags + passthrough quarter ->
//   MFMA (32/wave) -> park M quarter bf16 -> pairwise exp(-L1) on 16 b's ->
//   coalesced o_b stores.

namespace {
constexpr int kN = 32;
constexpr int kHW = 256;
constexpr int kF = 256;          // GEMM K
constexpr int kOutRow = 320;
constexpr int kMstride = 136;    // ushorts/row: 128 + 8 pad (272 B, 16B-aligned)
constexpr int kOstride = 24;     // floats/row in obuf (96 B; 2*24 mod 32 = 16 -> 2-way free)
}

using frag_ab = __attribute__((ext_vector_type(8))) short;   // 8 bf16
using frag_cd = __attribute__((ext_vector_type(4))) float;   // 4 f32

__device__ inline unsigned short f2bf(float f) {
  union { __hip_bfloat16 h; unsigned short u; } c;
  c.h = __float2bfloat16(f);
  return c.u;
}

__device__ inline void unpack8(const uint4& m, float* f) {
  f[0] = __uint_as_float(m.x << 16);  f[1] = __uint_as_float(m.x & 0xffff0000u);
  f[2] = __uint_as_float(m.y << 16);  f[3] = __uint_as_float(m.y & 0xffff0000u);
  f[4] = __uint_as_float(m.z << 16);  f[5] = __uint_as_float(m.z & 0xffff0000u);
  f[6] = __uint_as_float(m.w << 16);  f[7] = __uint_as_float(m.w & 0xffff0000u);
}

// ---- Kernel 1: pack T into MFMA B-fragments (no LDS, no barriers) ----
__global__ __launch_bounds__(256)
void pack_T(const float* __restrict__ T, uint4* __restrict__ Tf) {
  const int g = blockIdx.x * 256 + threadIdx.x;  // 0..16383
  const int l = g & 63;
  const int frag = g >> 6;                       // 0..255 = tt*8 + kt
  const int tt = frag >> 3, kt = frag & 7;
  const int col = tt * 16 + (l & 15);
  const int k0 = kt * 32 + (l >> 4) * 8;
  unsigned p[4];
#pragma unroll
  for (int jj = 0; jj < 4; ++jj) {
    float a = T[(size_t)(k0 + jj * 2) * 512 + col];
    float b = T[(size_t)(k0 + jj * 2 + 1) * 512 + col];
    p[jj] = (unsigned)f2bf(a) | ((unsigned)f2bf(b) << 16);
  }
  Tf[g] = make_uint4(p[0], p[1], p[2], p[3]);
}

// ---- Kernel 2: fused GEMM + pairwise, one t-quarter per block ----
__global__ __launch_bounds__(256, 4)
void mbd_main(const float* __restrict__ x, const uint4* __restrict__ Tf,
              float* __restrict__ out) {
  __shared__ uint4 Afrag[2 * 8 * 64];                           // 16 KB
  __shared__ __align__(16) unsigned short Mlds[kN * kMstride];  // 8.7 KB
  float* obuf = (float*)Afrag;                                  // [32][24] alias
  const int hw = blockIdx.x & (kHW - 1);
  const int qg = blockIdx.x >> 8;          // t-quarter 0..3 (16 b's, 128 t-cols)
  const int tid = threadIdx.x;
  const int l = tid & 63, w = tid >> 6;    // 4 waves

  // Phase 0: prefetch this wave's B-fragments (independent of barriers; their
  // L2 latency hides behind phase 1's global traffic).
  uint4 bfr[2][8];
#pragma unroll
  for (int q = 0; q < 2; ++q)
#pragma unroll
    for (int kt = 0; kt < 8; ++kt) {
      const int tT = qg * 8 + w * 2 + q;   // global t-tile 0..31
      bfr[q][kt] = Tf[(tT * 8 + kt) * 64 + l];
    }

  // Phase 1: stage x -> A-frags (bf16) + passthrough this quarter's features.
  const float4* x4 = (const float4*)x;
  float4* out4 = (float4*)out;
#pragma unroll
  for (int s = 0; s < 4; ++s) {
    const int task = tid + s * 256;        // 1024 tasks: 32 n x 32 k-groups
    const int n = task >> 5;
    const int k8 = task & 31;              // group of 8 features
    const size_t xb = (size_t)n * (kHW * kF / 4) + (size_t)hw * (kF / 4) + k8 * 2;
    float4 v0 = x4[xb];
    float4 v1 = x4[xb + 1];
    if ((k8 >> 3) == qg) {                 // this block's quarter of features
      const size_t ob = (size_t)(n * kHW + hw) * (kOutRow / 4) + k8 * 2;
      out4[ob] = v0;
      out4[ob + 1] = v1;
    }
    uint4 p;
    p.x = (unsigned)f2bf(v0.x) | ((unsigned)f2bf(v0.y) << 16);
    p.y = (unsigned)f2bf(v0.z) | ((unsigned)f2bf(v0.w) << 16);
    p.z = (unsigned)f2bf(v1.x) | ((unsigned)f2bf(v1.y) << 16);
    p.w = (unsigned)f2bf(v1.z) | ((unsigned)f2bf(v1.w) << 16);
    const int rt = n >> 4, kt = k8 >> 2, ln = (n & 15) | ((k8 & 3) << 4);
    Afrag[(rt * 8 + kt) * 64 + ln] = p;
  }
  __syncthreads();

  // Phase 2: MFMA GEMM; wave w owns t-tiles qg*8 + {2w, 2w+1}.
  frag_cd acc[2][2] = {};                  // [q][rt]
#pragma unroll
  for (int kt = 0; kt < 8; ++kt) {
    uint4 a0 = Afrag[(0 * 8 + kt) * 64 + l];
    uint4 a1 = Afrag[(1 * 8 + kt) * 64 + l];
    frag_ab af0 = __builtin_bit_cast(frag_ab, a0);
    frag_ab af1 = __builtin_bit_cast(frag_ab, a1);
#pragma unroll
    for (int q = 0; q < 2; ++q) {
      frag_ab bf = __builtin_bit_cast(frag_ab, bfr[q][kt]);
      acc[q][0] = __builtin_amdgcn_mfma_f32_16x16x32_bf16(af0, bf, acc[q][0], 0, 0, 0);
      acc[q][1] = __builtin_amdgcn_mfma_f32_16x16x32_bf16(af1, bf, acc[q][1], 0, 0, 0);
    }
  }

  // Phase 3a: park M quarter (bf16). C/D: col = l&15, row = (l>>4)*4 + r.
#pragma unroll
  for (int q = 0; q < 2; ++q)
#pragma unroll
    for (int rt = 0; rt < 2; ++rt)
#pragma unroll
      for (int r = 0; r < 4; ++r) {
        const int n = rt * 16 + (l >> 4) * 4 + r;
        const int t = (w * 2 + q) * 16 + (l & 15);  // local col 0..127
        Mlds[n * kMstride + t] = f2bf(acc[q][rt][r]);
      }
  __syncthreads();

  // Phase 3b: pairwise exp(-L1). Thread: local b = tid>>4 (0..15), i in {i0,i0+1}.
  const int b = tid >> 4;
  const int i0 = (tid & 15) * 2;
  float mi[2][8];
#pragma unroll
  for (int ii = 0; ii < 2; ++ii) {
    uint4 m = *(const uint4*)&Mlds[(i0 + ii) * kMstride + b * 8];
    unpack8(m, mi[ii]);
  }
  float ob0 = 0.f, ob1 = 0.f;
#pragma unroll 4
  for (int j = 0; j < kN; ++j) {
    uint4 m = *(const uint4*)&Mlds[j * kMstride + b * 8];  // 16-lane broadcast
    float mj[8];
    unpack8(m, mj);
    float n0 = 0.f, n1 = 0.f;
#pragma unroll
    for (int c = 0; c < 8; ++c) {
      n0 += fabsf(mi[0][c] - mj[c]);
      n1 += fabsf(mi[1][c] - mj[c]);
    }
    ob0 += __expf(-n0);
    ob1 += __expf(-n1);
  }
  obuf[i0 * kOstride + b] = ob0;           // aliased over dead Afrag
  obuf[(i0 + 1) * kOstride + b] = ob1;
  __syncthreads();

  // Phase 3c: coalesced o_b stores (32 n x 4 float4 per block).
  if (tid < 128) {
    const int n = tid >> 2;
    const int b4 = tid & 3;
    float4 v = *(const float4*)&obuf[n * kOstride + b4 * 4];
    out4[(size_t)(n * kHW + hw) * (kOutRow / 4) + (kF / 4) + qg * 4 + b4] = v;
  }
}

extern "C" void kernel_launch(void* const* d_in, const int* in_sizes, int n_in,
                              void* d_out, int out_size, void* d_ws, size_t ws_size,
                              hipStream_t stream) {
  const float* x = (const float*)d_in[0];     // [32,16,16,256]
  const float* T = (const float*)d_in[1];     // [256,64,8] = [256][512]
  float* out = (float*)d_out;                 // [32,16,16,320]
  uint4* Tf = (uint4*)d_ws;                   // 256 KB of B-fragments
  (void)in_sizes; (void)n_in; (void)out_size; (void)ws_size;
  pack_T<<<dim3(64), dim3(256), 0, stream>>>(T, Tf);
  mbd_main<<<dim3(4 * kHW), dim3(256), 0, stream>>>(x, Tf, out);
}